// Round 10
// baseline (127.961 us; speedup 1.0000x reference)
//
#include <hip/hip_runtime.h>

// Problem constants: B=4, N=1024, D=256, H=8
// q/k/v stored bf16 in qkvb[seg][tok][h*256+d]  (tok-major, stride 2048),
// tok = b*1024+n.  Wqkv pre-transposed + column-permuted: whT row
// p = seg*2048+h*256+d holds original column seg*2048+d*8+h.  W0
// pre-transposed with the same k-permutation: w0T[e][h*256+d] = W0[d*8+h][e].
// Softmax: NO max subtraction (|s| <~ 0.6, exp safe); q pre-scaled by D^-0.5.
// R9: diag row-scaling commutes through W0 within a head -> y_h = v_h @ W0_h
// is scores-independent; scores (2048) + y (512) fused in ONE 2560-block
// launch; dg = exp(sd)/sum(pl) applied in reduce_out (f32).
// R15/R16 (verified, 124.9us): BK=64, XOR swizzle (physical 16B-slot =
// logical ^ (row&7); inverse-swizzled global source, same XOR on read),
// 4 j-groups x 32 rows staging (8 global_load_lds/lane/K-tile).
// R17 (T4 counted vmcnt): double-buffer + NEVER drain freshly-issued loads.
// Per iter: compute(buf[kt&1]) ; s_barrier (closes reads) ;
// stage(kt+2 -> buf[kt&1]) ; s_waitcnt vmcnt(8) (waits ONLY tile kt+1's
// loads, issued one compute phase ago) ; s_barrier.  K=256 = 4 tiles:
// kt=0,1 stage t2,t3; kt=2 drains vmcnt(0) (t3); kt=3 computes clean.
// R5's dbuf failed because __syncthreads drains vmcnt(0) incl. the fresh
// prefetch -- raw s_barrier + counted vmcnt is the fix.  LDS 66KB ->
// 2 blocks/CU (TLP->ILP trade, m218).
// R18: R9 bench was an infra failure (container died pre-test); schedule
// re-audited (uniform barriers, monotone vmcnt, intrinsics not reorderable)
// -- resubmitted unchanged.
// NOTE (R8/R12): acc[4][4] of float4 = 64 VGPRs max safe accumulator;
// 256^2 tiles can't fit the occupancy budget at K=256.

#define SEGSZ 8388608  // elements per q/k/v segment = 4096 tok * 2048

typedef short v8s __attribute__((ext_vector_type(8)));
typedef float v4f __attribute__((ext_vector_type(4)));

__device__ __forceinline__ ushort f2bf(float v) {
  union { float f; unsigned u; } x; x.f = v;
  const unsigned r = x.u + 0x7fff + ((x.u >> 16) & 1);   // RTNE
  return (ushort)(r >> 16);
}
__device__ __forceinline__ float bf2f(ushort v) {
  union { unsigned u; float f; } x; x.u = ((unsigned)v) << 16;
  return x.f;
}

#define GLOAD_LDS16(g, l)                                            \
  __builtin_amdgcn_global_load_lds(                                  \
      (const __attribute__((address_space(1))) void*)(g),            \
      (__attribute__((address_space(3))) void*)(l), 16, 0, 0)

#define SBAR()   __builtin_amdgcn_s_barrier()
#define VMCNT8() asm volatile("s_waitcnt vmcnt(8)" ::: "memory")
#define VMCNT0() asm volatile("s_waitcnt vmcnt(0)" ::: "memory")

// ---------------------------------------------------------------------------
// prep: fused conversions.  blocks 0..1023: x->xb (bf16).
// blocks 1024..1407: Wqkv transpose+permute -> whT.
// blocks 1408..1535: W0 transpose+permute -> w0T.  grid (1536), 256 thr.
// ---------------------------------------------------------------------------
__global__ __launch_bounds__(256) void prep(
    const float* __restrict__ X, const float* __restrict__ Wqkv,
    const float* __restrict__ W0, ushort* __restrict__ xb,
    ushort* __restrict__ whT, ushort* __restrict__ w0T) {
  __shared__ float T[64][65];
  const int tid = threadIdx.x;
  int bid = blockIdx.x;

  if (bid < 1024) {  // ---- x -> bf16 ----
    const size_t i = ((size_t)bid * 256 + tid) * 4;
    const float4 v = *(const float4*)&X[i];
    ushort4 hv = {f2bf(v.x), f2bf(v.y), f2bf(v.z), f2bf(v.w)};
    *(ushort4*)&xb[i] = hv;
    return;
  }
  bid -= 1024;
  if (bid < 384) {  // ---- Wqkv [256][6144] -> whT [6144][256], permuted ----
    const int n0 = (bid % 96) * 64;
    const int k0 = (bid / 96) * 64;
    {
      const int row = tid >> 2;
      const int c0 = (tid & 3) * 16;
#pragma unroll
      for (int j = 0; j < 16; j += 4) {
        const float4 v = *(const float4*)&Wqkv[(size_t)(k0 + row) * 6144 + n0 + c0 + j];
        T[row][c0 + j + 0] = v.x; T[row][c0 + j + 1] = v.y;
        T[row][c0 + j + 2] = v.z; T[row][c0 + j + 3] = v.w;
      }
    }
    __syncthreads();
    {
      const int nn = tid >> 2;
      const int kk0 = (tid & 3) * 16;
      const int n = n0 + nn;
      const int seg = n >> 11, h = n & 7, d = (n & 2047) >> 3;
      const int p = seg * 2048 + h * 256 + d;
      ushort hv[16];
#pragma unroll
      for (int j = 0; j < 16; ++j) hv[j] = f2bf(T[kk0 + j][nn]);
      const size_t base = (size_t)p * 256 + k0 + kk0;
#pragma unroll
      for (int j = 0; j < 16; j += 8) *(v8s*)&whT[base + j] = *(v8s*)&hv[j];
    }
    return;
  }
  bid -= 384;
  {  // ---- W0 [2048][256] -> w0T [256][2048], k-permuted ----
    const int e0 = (bid & 3) * 64;
    const int k0 = (bid >> 2) * 64;
    {
      const int row = tid >> 2;
      const int c0 = (tid & 3) * 16;
#pragma unroll
      for (int j = 0; j < 16; j += 4) {
        const float4 v = *(const float4*)&W0[(size_t)(k0 + row) * 256 + e0 + c0 + j];
        T[row][c0 + j + 0] = v.x; T[row][c0 + j + 1] = v.y;
        T[row][c0 + j + 2] = v.z; T[row][c0 + j + 3] = v.w;
      }
    }
    __syncthreads();
    {
      const int ee = tid >> 2;
      const int kk0 = (tid & 3) * 16;
#pragma unroll
      for (int j = 0; j < 16; ++j) {
        const int k = k0 + kk0 + j;      // original row = d*8+h
        const int d = k >> 3, h = k & 7;
        w0T[(size_t)(e0 + ee) * 2048 + h * 256 + d] = f2bf(T[kk0 + j][ee]);
      }
    }
  }
}

// ---------------------------------------------------------------------------
// 128x128 tile, BK=64, 4 waves (256 thr), DOUBLE-buffer counted-vmcnt
// K-loop, K=256 (4 K-tiles, tile kt lives in buf kt&1).  LDS A/B:
// [2][128 rows][64 cols] bf16 = 32KB each.  Swizzle as R15/R16.
// ---------------------------------------------------------------------------
template <int STRIDE>
__device__ __forceinline__ void gemm128_k64(
    const ushort* __restrict__ gA, const ushort* __restrict__ gB,
    ushort (&AS)[2][8192], ushort (&BS)[2][8192], v4f (&acc)[4][4]) {
  const int tid = threadIdx.x;
  const int wave = tid >> 6, lane = tid & 63;
  const int quad = lane >> 4, l15 = lane & 15;
  const int wr = (wave >> 1) * 64;
  const int wc = (wave & 1) * 64;
  const int srow = lane >> 3;                     // row within 8-row group
  const int scol = (((lane & 7) ^ srow) << 3);    // inverse-swizzled col

  auto stage = [&](int kt, int bi) {
#pragma unroll
    for (int j = 0; j < 4; ++j) {   // rows j*32 + wave*8 + srow  (4 waves)
      const size_t grow =
          (size_t)(j * 32 + wave * 8 + srow) * STRIDE + kt * 64 + scol;
      GLOAD_LDS16(gA + grow, &AS[bi][j * 2048 + wave * 512]);
      GLOAD_LDS16(gB + grow, &BS[bi][j * 2048 + wave * 512]);
    }
  };

  stage(0, 0);
  stage(1, 1);
  VMCNT8();    // t0's 8 loads landed (t1's may remain in flight)
  SBAR();

#pragma unroll
  for (int kt = 0; kt < 4; ++kt) {
    const int cur = kt & 1;
#pragma unroll
    for (int ks = 0; ks < 2; ++ks) {
      v8s aF[4], bF[4];
      const int rx = l15 & 7;
#pragma unroll
      for (int i = 0; i < 4; ++i) {
        aF[i] = *(const v8s*)&AS[cur][(wr + i * 16 + l15) * 64 +
                                      ((((ks << 2) | quad) ^ rx) << 3)];
        bF[i] = *(const v8s*)&BS[cur][(wc + i * 16 + l15) * 64 +
                                      ((((ks << 2) | quad) ^ rx) << 3)];
      }
#pragma unroll
      for (int ri = 0; ri < 4; ++ri)
#pragma unroll
        for (int ci = 0; ci < 4; ++ci)
          acc[ri][ci] = __builtin_amdgcn_mfma_f32_16x16x32_bf16(
              aF[ri], bF[ci], acc[ri][ci], 0, 0, 0);
    }
    if (kt < 3) {
      SBAR();                    // all waves done reading buf[cur]
      if (kt < 2) {
        stage(kt + 2, cur);      // overwrite buf[cur] with tile kt+2
        VMCNT8();                // wait ONLY tile kt+1's loads (issued 1
      } else {                   //   compute phase ago -> mostly landed)
        VMCNT0();                // last outstanding: tile 3
      }
      SBAR();                    // everyone's waits done -> next buf ready
    }
  }
}

// ---------------------------------------------------------------------------
// Kernel A: qkv = x @ Wqkv + bqkv.  grid (48, 32), 256 thr, 128x128 tile.
// ---------------------------------------------------------------------------
__global__ __launch_bounds__(256) void qkv_mfma(
    const ushort* __restrict__ xb, const ushort* __restrict__ whT,
    const float* __restrict__ bias, ushort* __restrict__ qkvb) {
  __shared__ ushort As[2][8192];
  __shared__ ushort Bh[2][8192];
  const int tid = threadIdx.x;
  const int wave = tid >> 6, lane = tid & 63;
  const int quad = lane >> 4, l15 = lane & 15;
  const int c0 = blockIdx.x * 128;
  const int r0 = blockIdx.y * 128;
  const int wr = (wave >> 1) * 64;
  const int wc = (wave & 1) * 64;

  v4f acc[4][4] = {};
  gemm128_k64<256>(xb + (size_t)r0 * 256, whT + (size_t)c0 * 256, As, Bh, acc);

  // Epilogue: C layout col=l15, row=quad*4+reg.  c' = seg*2048 + h*256 + d.
#pragma unroll
  for (int ci = 0; ci < 4; ++ci) {
    const int c = c0 + wc + ci * 16 + l15;
    const int cseg = c >> 11;
    const int h = (c & 2047) >> 8;
    const int d = c & 255;
    const float bv = bias[cseg * 2048 + d * 8 + h];
#pragma unroll
    for (int ri = 0; ri < 4; ++ri)
#pragma unroll
      for (int rg = 0; rg < 4; ++rg) {
        const int r = r0 + wr + ri * 16 + quad * 4 + rg;
        const int g = r * 3 + cseg;
        const int seg = g >> 12;       // q/k/v
        const int tok = g & 4095;      // = b*1024 + n
        float val = acc[ri][ci][rg] + bv;
        if (seg == 0) val *= 0.0625f;  // pre-scale q by D^-0.5
        qkvb[(size_t)seg * SEGSZ + (size_t)tok * 2048 + h * 256 + d] = f2bf(val);
      }
  }
}

// ---------------------------------------------------------------------------
// Kernel B (fused): blocks 0..2047 = bf16 MFMA score stats; blocks
// 2048..2559 = y_h = v_h @ W0_h partials (no dg).
// Scores ids keep id%8 == bh%8 (XCD L2 swizzle); y blocks fill the tail.
// ---------------------------------------------------------------------------
__global__ __launch_bounds__(256) void mid_fused(
    const ushort* __restrict__ qkvb, const ushort* __restrict__ w0T,
    float* __restrict__ pl, float* __restrict__ sd_ws,
    ushort* __restrict__ partial) {
  __shared__ ushort S1[2][8192];
  __shared__ ushort S2[2][8192];
  __shared__ float redL[2][2][64];

  const int tid = threadIdx.x;
  const int wave = tid >> 6, lane = tid & 63;
  const int quad = lane >> 4, l15 = lane & 15;
  const int wr = (wave >> 1) * 64;
  const int wc = (wave & 1) * 64;
  const int id = blockIdx.x;

  v4f acc[4][4] = {};

  if (id < 2048) {
    // ---------------- scores branch ----------------
    const int bh = (id >> 9) * 8 + (id & 7);
    const int tile = (id >> 3) & 63;
    const int tt0 = (tile >> 3) * 128;
    const int nn0 = (tile & 7) * 128;    // n-tile inner: k-tile L2 reuse
    const int b = bh >> 3, h = bh & 7;
    const ushort* Qg = qkvb + (size_t)b * 1024 * 2048 + h * 256;
    const ushort* Kg = Qg + SEGSZ;

    gemm128_k64<2048>(Qg + (size_t)nn0 * 2048, Kg + (size_t)tt0 * 2048,
                      S1, S2, acc);

    // ---- column sum of exp(s).  C layout: col = l15, row = quad*4 + reg ----
    float lsum[4];
#pragma unroll
    for (int ci = 0; ci < 4; ++ci) {
      float s = 0.f;
#pragma unroll
      for (int ri = 0; ri < 4; ++ri)
#pragma unroll
        for (int rg = 0; rg < 4; ++rg) s += __expf(acc[ri][ci][rg]);
      s += __shfl_xor(s, 16, 64);
      s += __shfl_xor(s, 32, 64);
      lsum[ci] = s;                      // sum over this wave's 64 rows
    }
    if (quad == 0) {
#pragma unroll
      for (int ci = 0; ci < 4; ++ci)
        redL[wave & 1][wave >> 1][ci * 16 + l15] = lsum[ci];
    }
    __syncthreads();
    if ((wave >> 1) == 0 && quad == 0) {
#pragma unroll
      for (int ci = 0; ci < 4; ++ci) {
        const int t = tt0 + (wave & 1) * 64 + ci * 16 + l15;
        const float l = lsum[ci] + redL[wave & 1][1][ci * 16 + l15];
        pl[((size_t)bh * 1024 + t) * 8 + (tile & 7)] = l;
      }
    }

    // ---- diagonal capture (tt0 == nn0 tiles) ----
    if (tt0 == nn0 && (wave == 0 || wave == 3) && quad == (l15 >> 2)) {
#pragma unroll
      for (int ri = 0; ri < 4; ++ri) {
        const int t = tt0 + (wave & 1) * 64 + ri * 16 + l15;
        sd_ws[(size_t)bh * 1024 + t] = acc[ri][ri][l15 & 3];
      }
    }
  } else {
    // ---------------- y = v_h @ W0_h branch (no dg) ----------------
    const int j = id - 2048;
    const int e0 = (j & 1) * 128;
    const int tok0 = ((j >> 1) & 31) * 128;
    const int h = j >> 6;
    const ushort* vb = qkvb + 2 * (size_t)SEGSZ;

    gemm128_k64<2048>(vb + (size_t)tok0 * 2048 + h * 256,
                      w0T + (size_t)e0 * 2048 + h * 256, S1, S2, acc);

#pragma unroll
    for (int ri = 0; ri < 4; ++ri)
#pragma unroll
      for (int rg = 0; rg < 4; ++rg) {
        const int lrow = wr + ri * 16 + quad * 4 + rg;
        const int tok = tok0 + lrow;
#pragma unroll
        for (int ci = 0; ci < 4; ++ci) {
          const int e = e0 + wc + ci * 16 + l15;
          partial[(size_t)h * 1048576 + (size_t)tok * 256 + e] =
              f2bf(acc[ri][ci][rg]);
        }
      }
  }
}

// ---------------------------------------------------------------------------
// Fallback kernels (workspace too small for partials): atomic av with
// in-kernel diag.  Not used on the benched path.
// ---------------------------------------------------------------------------
__global__ __launch_bounds__(256) void av_atomic(
    const ushort* __restrict__ vb, const ushort* __restrict__ w0T,
    const float* __restrict__ pl, const float* __restrict__ sd,
    float* __restrict__ out) {
  __shared__ ushort As[2][8192];
  __shared__ ushort Bs[2][8192];
  __shared__ float diagS[128];
  const int tid = threadIdx.x;
  const int wave = tid >> 6, lane = tid & 63;
  const int quad = lane >> 4, l15 = lane & 15;
  const int e0 = blockIdx.x * 128;
  const int tok0 = blockIdx.y * 128;
  const int h = blockIdx.z;
  const int wr = (wave >> 1) * 64;
  const int wc = (wave & 1) * 64;

  if (tid < 128) {
    const int bh = (tok0 >> 10) * 8 + h;
    const int t = (tok0 & 1023) + tid;
    const size_t base = ((size_t)bh * 1024 + t) * 8;
    float l = 0.f;
#pragma unroll
    for (int c = 0; c < 8; ++c) l += pl[base + c];
    diagS[tid] = __expf(sd[(size_t)bh * 1024 + t]) / l;
  }
  __syncthreads();

  v4f acc[4][4] = {};
  gemm128_k64<2048>(vb + (size_t)tok0 * 2048 + h * 256,
                    w0T + (size_t)e0 * 2048 + h * 256, As, Bs, acc);

#pragma unroll
  for (int ri = 0; ri < 4; ++ri)
#pragma unroll
    for (int rg = 0; rg < 4; ++rg) {
      const int lrow = wr + ri * 16 + quad * 4 + rg;
      const int tok = tok0 + lrow;
      const float dg = diagS[lrow];
#pragma unroll
      for (int ci = 0; ci < 4; ++ci) {
        const int e = e0 + wc + ci * 16 + l15;
        atomicAdd(&out[(size_t)tok * 256 + e], acc[ri][ci][rg] * dg);
      }
    }
}

__global__ void init_out(const float* __restrict__ b0, float* __restrict__ out) {
  const int i = blockIdx.x * 256 + threadIdx.x;
  const int e0 = (i & 63) << 2;
  *(float4*)&out[(size_t)i * 4] = *(const float4*)&b0[e0];
}

// ---------------------------------------------------------------------------
// reduce_out: out[tok][e] = b0[e] + sum_h dg_h(tok) * y_h[tok][e].
// dg computed per-block in LDS: block covers 4 tokens (256 float4-groups).
// ---------------------------------------------------------------------------
__global__ void reduce_out(const ushort* __restrict__ partial,
                           const float* __restrict__ pl,
                           const float* __restrict__ sd,
                           const float* __restrict__ b0, float* __restrict__ out) {
  __shared__ float dgS[32];
  const int i = blockIdx.x * 256 + threadIdx.x;  // 262144 float4 groups
  const int tbase = blockIdx.x * 4;              // 4 tokens per block
  if (threadIdx.x < 32) {
    const int tl = threadIdx.x >> 3, h = threadIdx.x & 7;
    const int tok = tbase + tl;
    const int bh = (tok >> 10) * 8 + h;
    const int t = tok & 1023;
    const size_t base = ((size_t)bh * 1024 + t) * 8;
    float l = 0.f;
#pragma unroll
    for (int c = 0; c < 8; ++c) l += pl[base + c];
    dgS[threadIdx.x] = __expf(sd[(size_t)bh * 1024 + t]) / l;
  }
  __syncthreads();
  const int tl = threadIdx.x >> 6;
  const int e0 = (i & 63) << 2;
  float4 a = *(const float4*)&b0[e0];
#pragma unroll
  for (int h = 0; h < 8; ++h) {
    const float dg = dgS[tl * 8 + h];
    const ushort4 p = *(const ushort4*)&partial[(size_t)h * 1048576 + (size_t)i * 4];
    a.x += dg * bf2f(p.x); a.y += dg * bf2f(p.y);
    a.z += dg * bf2f(p.z); a.w += dg * bf2f(p.w);
  }
  *(float4*)&out[(size_t)i * 4] = a;
}

extern "C" void kernel_launch(void* const* d_in, const int* in_sizes, int n_in,
                              void* d_out, int out_size, void* d_ws, size_t ws_size,
                              hipStream_t stream) {
  const float* x    = (const float*)d_in[0];
  const float* Wqkv = (const float*)d_in[1];
  const float* bqkv = (const float*)d_in[2];
  const float* W0   = (const float*)d_in[3];
  const float* b0   = (const float*)d_in[4];
  float* out = (float*)d_out;

  float*  pl   = (float*)d_ws;                     // 262144 f
  float*  sd   = pl + 262144;                      // 32768 f
  ushort* qkvb = (ushort*)(sd + 32768);            // 3*SEGSZ us (q|k|v)
  ushort* xb   = qkvb + 3 * (size_t)SEGSZ;         // 1048576 us
  ushort* whT  = xb + 1048576;                     // 1572864 us
  ushort* w0T  = whT + 1572864;                    // 524288 us
  ushort* partial = w0T + 524288;                  // 8*1048576 us (optional)

  ushort* vb = qkvb + 2 * (size_t)SEGSZ;

  const size_t need_base =
      (size_t)(262144 + 32768) * 4 + (size_t)SEGSZ * 3 * 2 +
      (size_t)(1048576 + 1572864 + 524288) * 2;
  const bool full = ws_size >= need_base + (size_t)8 * 1048576 * 2;

  prep<<<1536, 256, 0, stream>>>(x, Wqkv, W0, xb, whT, w0T);
  qkv_mfma<<<dim3(48, 32), 256, 0, stream>>>(xb, whT, bqkv, qkvb);
  if (full) {
    mid_fused<<<2560, 256, 0, stream>>>(qkvb, w0T, pl, sd, partial);
    reduce_out<<<1024, 256, 0, stream>>>(partial, pl, sd, b0, out);
  } else {
    mid_fused<<<2048, 256, 0, stream>>>(qkvb, w0T, pl, sd, nullptr);
    init_out<<<1024, 256, 0, stream>>>(b0, out);
    av_atomic<<<dim3(2, 32, 8), 256, 0, stream>>>(vb, w0T, pl, sd, out);
  }
}